// Round 18
// baseline (363.108 us; speedup 1.0000x reference)
//
#include <hip/hip_runtime.h>
#include <stdint.h>

#define T_STEPS 256
#define F_IN 64
#define L2E 1.44269504f

typedef __bf16 bf16x8 __attribute__((ext_vector_type(8)));
typedef float f32x4 __attribute__((ext_vector_type(4)));
typedef uint32_t u32;

#define GLDS16(gp, lp)                                                         \
    __builtin_amdgcn_global_load_lds(                                          \
        (const __attribute__((address_space(1))) unsigned int*)(gp),           \
        (__attribute__((address_space(3))) unsigned int*)(lp), 16, 0, 0)

static __device__ __forceinline__ u32 pk2(float lo, float hi) {
    unsigned short a = __builtin_bit_cast(unsigned short, (__bf16)lo);
    unsigned short b = __builtin_bit_cast(unsigned short, (__bf16)hi);
    return (u32)a | ((u32)b << 16);
}

// 8-ROW waves -> 2048 waves = 2 independent recurrence chains per SIMD with
// ALL SIMDs fed (the untested quadrant). Batch cols 8..15 duplicate cols 0..7
// (identical values, column-isolated; never stored). x traffic exact: lanes
// cl>=8 duplicate lane cl-8's addresses (coalesced away).
// SPILL-PROOFED vs R16 (tripwire race = spill ops poisoning counted vmcnt):
//  * single-STEP `unroll 1` loop, runtime (SGPR) slot arithmetic
//  * Wd/bd loads moved to epilogue (not live across loop)
//  -> est. peak ~210 VGPR < 256 cap, so vmcnt counting is exact again.
// Everything else: no barriers, no h-LDS, select-after-shuffle h exchange,
// merged cell, bias via MFMA C-operand, scaled-W, XOR-both-sides LDS staging
// ([8 rows][8 chunks]x2 halves; chunk c of row r holds global chunk c^r;
// reader applies same XOR).
__global__ __launch_bounds__(256, 2)
void lstm_fused(const float* __restrict__ x,
                const float* __restrict__ Wl,   // [96][128]
                const float* __restrict__ bl,   // [128]
                const float* __restrict__ Wd,   // [32]
                const float* __restrict__ bd,   // [1]
                float* __restrict__ out)        // [B]
{
    __shared__ __align__(16) float xs[4][4][512];   // [wave][slot][2KB] = 32 KB/block

    const int lane = threadIdx.x & 63;
    const int wid  = threadIdx.x >> 6;
    const int cl   = lane & 15;
    const int g4   = lane >> 4;
    const int rowBase = blockIdx.x * 32 + wid * 8;

#define GSC(q) (((q) >> 1) == 1 ? -2.0f * L2E : -L2E)

    // ---- 24 pre-scaled W^T A-fragments (standard K-row order) ----
    bf16x8 wfrag[3][8];
#pragma unroll
    for (int kc = 0; kc < 3; ++kc) {
#pragma unroll
        for (int q = 0; q < 8; ++q) {
            bf16x8 v;
#pragma unroll
            for (int j = 0; j < 8; ++j)
                v[j] = (__bf16)(GSC(q) * Wl[(kc * 32 + g4 * 8 + j) * 128 + q * 16 + cl]);
            wfrag[kc][q] = v;
        }
    }

    // ---- pre-scaled bias as MFMA C-init ----
    f32x4 biasf[8];
#pragma unroll
    for (int q = 0; q < 8; ++q) {
#pragma unroll
        for (int r = 0; r < 4; ++r) {
            const int gate = q * 16 + g4 * 4 + r;
            biasf[q][r] = GSC(q) * (bl[gate] + ((q >> 1) == 2 ? 1.0f : 0.0f));
        }
    }

    // staging base: lane l -> row l>>3, global chunk (l&7)^((l>>3)&7), LDS chunk l&7
    const char* xbyte = (const char*)(x + (size_t)(rowBase + (lane >> 3)) * (size_t)(T_STEPS * F_IN))
                      + (size_t)((((lane & 7) ^ ((lane >> 3) & 7)) << 4));

    // phase stagger: the 2 co-resident blocks (b, b+256) start ~900 cyc apart
    if ((blockIdx.x >> 8) & 1) __builtin_amdgcn_s_sleep(14);

    asm volatile("s_waitcnt vmcnt(0)" ::: "memory");   // drain setup loads: exact counting
    __builtin_amdgcn_sched_barrier(0);

#define STAGE(TT, SP) do {                                                     \
    const char* gp = xbyte + (size_t)(TT) * 256;                               \
    GLDS16(gp,       &xs[wid][SP][0]);                                         \
    GLDS16(gp + 128, &xs[wid][SP][256]);                                       \
} while (0)

    STAGE(0, 0);
    STAGE(1, 1);
    STAGE(2, 2);

    // shuffle-exchange constants (batch-column-local; cols 8..15 mirror 0..7)
    const int srcA = cl + 32 * (g4 & 1);
    const int srcB = srcA + 16;
    const int sel  = g4 >> 1;
    const int r7   = cl & 7;
    const int offA = r7 * 32 + (((2 * g4) ^ r7) << 2);   // float idx, half 0

    f32x4 csl = {0.f, 0.f, 0.f, 0.f};   // c' = -2*L2E*c, units 4g4+r
    f32x4 csh = {0.f, 0.f, 0.f, 0.f};   // units 16+4g4+r
    f32x4 hlv = {0.f, 0.f, 0.f, 0.f};
    f32x4 hhv = {0.f, 0.f, 0.f, 0.f};
    u32 ahw0 = 0u, ahw1 = 0u, ahw2 = 0u, ahw3 = 0u;      // h0 = 0

#define CELL(AI, AJ, AF, AO, CS, HV) do {                                      \
    _Pragma("unroll")                                                          \
    for (int r = 0; r < 4; ++r) {                                              \
        float I  = __builtin_amdgcn_exp2f((AI)[r]);                            \
        float J  = __builtin_amdgcn_exp2f((AJ)[r]);                            \
        float Fv = __builtin_amdgcn_exp2f((AF)[r]);                            \
        float O  = __builtin_amdgcn_exp2f((AO)[r]);                            \
        float t3 = (1.0f + I) * (1.0f + J);                                    \
        float uu = 1.0f + Fv;                                                  \
        float np = __builtin_fmaf(J, 2.0f * L2E, -2.0f * L2E);                 \
        float r1 = __builtin_amdgcn_rcpf(t3 * uu);                             \
        float nm = __builtin_fmaf((CS)[r], t3, np * uu);                       \
        float cp = nm * r1;                                                    \
        float C  = __builtin_amdgcn_exp2f(cp);                                 \
        float r2 = __builtin_amdgcn_rcpf((1.0f + C) * (1.0f + O));             \
        (HV)[r] = (1.0f - C) * r2;                                             \
        (CS)[r] = cp;                                                          \
    }                                                                          \
} while (0)

    // single-body loop: runtime (SGPR) slot arithmetic, minimal live ranges
#pragma unroll 1
    for (int t = 0; t < T_STEPS; ++t) {
        // stage t+3, then wait: slots t and t+1 landed (margin = 2 ops)
        const int tpf = (t + 3 < T_STEPS) ? t + 3 : T_STEPS - 1;
        STAGE(tpf, (t + 3) & 3);
        asm volatile("s_waitcnt vmcnt(4)" ::: "memory");
        __builtin_amdgcn_sched_barrier(0);

        const float* sl = &xs[wid][t & 3][0];
        f32x4 xr0 = *(const f32x4*)(sl + offA);
        f32x4 xr1 = *(const f32x4*)(sl + (offA ^ 4));
        f32x4 xr2 = *(const f32x4*)(sl + 256 + offA);
        f32x4 xr3 = *(const f32x4*)(sl + 256 + (offA ^ 4));
        bf16x8 ax0, ax1;
#pragma unroll
        for (int j = 0; j < 4; ++j) {
            ax0[j]     = (__bf16)xr0[j];
            ax0[4 + j] = (__bf16)xr1[j];
            ax1[j]     = (__bf16)xr2[j];
            ax1[4 + j] = (__bf16)xr3[j];
        }

        union { u32 w[4]; bf16x8 v; } ahu;
        ahu.w[0] = ahw0; ahu.w[1] = ahw1; ahu.w[2] = ahw2; ahu.w[3] = ahw3;
        bf16x8 ah = ahu.v;

        f32x4 acc[8];
#pragma unroll
        for (int q = 0; q < 8; ++q) {
            f32x4 a = __builtin_amdgcn_mfma_f32_16x16x32_bf16(wfrag[0][q], ax0, biasf[q], 0, 0, 0);
            a = __builtin_amdgcn_mfma_f32_16x16x32_bf16(wfrag[1][q], ax1, a, 0, 0, 0);
            acc[q] = __builtin_amdgcn_mfma_f32_16x16x32_bf16(wfrag[2][q], ah, a, 0, 0, 0);
        }
        CELL(acc[0], acc[2], acc[4], acc[6], csl, hlv);
        CELL(acc[1], acc[3], acc[5], acc[7], csh, hhv);

        u32 W0 = pk2(hlv[0], hlv[1]);
        u32 W1 = pk2(hlv[2], hlv[3]);
        u32 W2 = pk2(hhv[0], hhv[1]);
        u32 W3 = pk2(hhv[2], hhv[3]);
        int A0 = __shfl((int)W0, srcA, 64), A1 = __shfl((int)W1, srcA, 64);
        int A2 = __shfl((int)W2, srcA, 64), A3 = __shfl((int)W3, srcA, 64);
        int B0 = __shfl((int)W0, srcB, 64), B1 = __shfl((int)W1, srcB, 64);
        int B2 = __shfl((int)W2, srcB, 64), B3 = __shfl((int)W3, srcB, 64);
        ahw0 = (u32)(sel ? A2 : A0);
        ahw1 = (u32)(sel ? A3 : A1);
        ahw2 = (u32)(sel ? B2 : B0);
        ahw3 = (u32)(sel ? B3 : B1);
    }
#undef CELL
#undef STAGE

    asm volatile("s_waitcnt vmcnt(0)" ::: "memory");   // drain tail glds

    // ---- epilogue: Wd/bd loaded HERE (not live across the loop) ----
    float v = 0.f;
#pragma unroll
    for (int r = 0; r < 4; ++r) {
        v = __builtin_fmaf(hlv[r], Wd[4 * g4 + r], v);
        v = __builtin_fmaf(hhv[r], Wd[16 + 4 * g4 + r], v);
    }
    v += __shfl_xor(v, 16, 64);
    v += __shfl_xor(v, 32, 64);
    if (lane < 8) {
        float z = v + bd[0];
        out[rowBase + lane] = z > 0.f ? z : (__expf(z) - 1.0f);
    }
}

extern "C" void kernel_launch(void* const* d_in, const int* in_sizes, int n_in,
                              void* d_out, int out_size, void* d_ws, size_t ws_size,
                              hipStream_t stream) {
    const float* x  = (const float*)d_in[0];
    const float* Wl = (const float*)d_in[1];
    const float* bl = (const float*)d_in[2];
    const float* Wd = (const float*)d_in[3];
    const float* bd = (const float*)d_in[4];
    float* out = (float*)d_out;

    const int rows = out_size;              // B = 16384
    const int grid = (rows + 31) / 32;      // 32 rows per 256-thread block (4 waves x 8)
    hipLaunchKernelGGL(lstm_fused, dim3(grid), dim3(256), 0, stream,
                       x, Wl, bl, Wd, bd, out);
}